// Round 14
// baseline (232.807 us; speedup 1.0000x reference)
//
#include <hip/hip_runtime.h>
#include <math.h>

// GlobalTransformer: B=2, T=16, N=256 (S=4096), H=64, NHEAD=4, dh=16, L=2
// Round 14: single persistent kernel (512 blocks = exact 2/CU co-residency),
// phases = round-11-verified bodies; grid barrier fixed: RELEASE add to
// signal, RELAXED RMW (add 0) to poll (coherent, no invalidate), single
// agent ACQUIRE fence on exit. 1 memset + 1 kernel launch.

namespace {
constexpr int T_ = 16, N_ = 256, S_ = 4096;
constexpr int PAIRS = 136;   // valid (tq,kt) pairs per bh (layer 0)
constexpr int NBLK = 512;

// ws float offsets
constexpr size_t OFF_A    = 0;        // [192]
constexpr size_t OFF_BT   = 192;      // [16][192]
constexpr size_t OFF_XB   = 3264;     // [16][64]
constexpr size_t OFF_X    = 5632;     // [B*S][64] (t=15 rows only)
constexpr size_t OFF_QKV  = 529920;   // [B*S][192]
constexpr size_t OFF_P0   = 2102784;  // [8][16][16][3][256]
constexpr size_t OFF_PM1  = 3675648;  // [128][256]
constexpr size_t OFF_PL1  = 3708416;  // [128][256]
constexpr size_t OFF_PA1  = 3741184;  // [128][256][16]
constexpr size_t OFF_WT   = 4265472;  // 98304 shorts
constexpr size_t OFF_BAR  = 4314624;  // 4 uints (grid barrier slots)

typedef float  f32x16 __attribute__((ext_vector_type(16)));
typedef short  short8 __attribute__((ext_vector_type(8)));

struct Args {
  const float *x_seq, *Wi, *bi, *Wqkv, *bqkv;
  const float *Wo0, *bo0, *g10, *be10, *W10, *b10, *W20, *b20, *g20, *be20;
  const float *Wo1, *bo1, *g11, *be11, *W11, *b11, *W21, *b21, *g21, *be21;
  const float *bq1;
  const float *dW1, *db1, *dW2, *db2, *dW3, *db3;
  float *A, *Bt, *Xb, *X, *QKV;
  float *P0, *PM1, *PL1, *PA1, *out;
  short *WT;
  unsigned *BAR;
};

__device__ inline float wave_sum(float v) {
#pragma unroll
  for (int off = 32; off > 0; off >>= 1) v += __shfl_xor(v, off, 64);
  return v;
}
__device__ inline unsigned bf16_rne(float f) {
  unsigned u = __float_as_uint(f);
  return (u + 0x7FFFu + ((u >> 16) & 1u)) >> 16;
}
__device__ inline unsigned pack2(float a, float b) {   // low<-a, high<-b
  return bf16_rne(a) | (bf16_rne(b) << 16);
}
__device__ inline f32x16 zero16() {
  f32x16 z;
#pragma unroll
  for (int i = 0; i < 16; ++i) z[i] = 0.f;
  return z;
}
__device__ inline float pe_val(int t, int h) {
  float div = __expf((float)(h & ~1) * (-0.14391156831212787f));
  float arg = (float)t * div;
  return (h & 1) ? cosf(arg) : sinf(arg);
}
__device__ inline float rebuild(short h, short l) {
  return __uint_as_float(((unsigned)(unsigned short)h) << 16) +
         __uint_as_float(((unsigned)(unsigned short)l) << 16);
}
__device__ __forceinline__ void split4_store(short* hp, short* lp,
                                             float v0, float v1, float v2, float v3) {
  unsigned u0 = __float_as_uint(v0), u1 = __float_as_uint(v1);
  unsigned u2 = __float_as_uint(v2), u3 = __float_as_uint(v3);
  float r0 = v0 - __uint_as_float(u0 & 0xFFFF0000u);
  float r1 = v1 - __uint_as_float(u1 & 0xFFFF0000u);
  float r2 = v2 - __uint_as_float(u2 & 0xFFFF0000u);
  float r3 = v3 - __uint_as_float(u3 & 0xFFFF0000u);
  *(uint2*)hp = make_uint2((u0 >> 16) | (u1 & 0xFFFF0000u),
                           (u2 >> 16) | (u3 & 0xFFFF0000u));
  *(uint2*)lp = make_uint2(pack2(r0, r1), pack2(r2, r3));
}
__device__ __forceinline__ f32x16 gemm_tile(
    const short* __restrict__ Wh, const short* __restrict__ Wl, int tileRow,
    int inDim, int nkt, const short* Bh, const short* Bl, int bstride,
    int l31, int hi) {
  f32x16 C = zero16();
  for (int kt = 0; kt < nkt; ++kt) {
    int ko = kt * 16 + 8 * hi;
    short8 Ah = *(const short8*)&Wh[tileRow * inDim + ko];
    short8 Al = *(const short8*)&Wl[tileRow * inDim + ko];
    short8 Bh8 = *(const short8*)&Bh[l31 * bstride + ko];
    short8 Bl8 = *(const short8*)&Bl[l31 * bstride + ko];
    C = __builtin_amdgcn_mfma_f32_32x32x16_bf16(Ah, Bh8, C, 0, 0, 0);
    C = __builtin_amdgcn_mfma_f32_32x32x16_bf16(Al, Bh8, C, 0, 0, 0);
    C = __builtin_amdgcn_mfma_f32_32x32x16_bf16(Ah, Bl8, C, 0, 0, 0);
  }
  return C;
}

// fixed grid barrier: RELEASE add to signal; RELAXED RMW poll (coherent,
// no cache-invalidate); one agent ACQUIRE fence after the flag is seen.
__device__ inline void grid_barrier(unsigned* bar, int idx) {
  __syncthreads();
  if (threadIdx.x == 0) {
    __threadfence();
    __hip_atomic_fetch_add(&bar[idx], 1u, __ATOMIC_RELEASE,
                           __HIP_MEMORY_SCOPE_AGENT);
    while (__hip_atomic_fetch_add(&bar[idx], 0u, __ATOMIC_RELAXED,
                                  __HIP_MEMORY_SCOPE_AGENT) < (unsigned)NBLK) {
      __builtin_amdgcn_s_sleep(64);
    }
    __builtin_amdgcn_fence(__ATOMIC_ACQUIRE, "agent");
  }
  __syncthreads();
}

__global__ __launch_bounds__(256, 2) void k_mega(Args P) {
  __shared__ __align__(16) char smem[56576];
  int blk = blockIdx.x, tid = threadIdx.x;

  // ================= phase S: setup (consumed only after barrier 0) ========
  {
    int t = blk;
    if (t < 16) {
      if (tid < 192) {
        float acc = P.bqkv[tid];
#pragma unroll 8
        for (int h = 0; h < 64; ++h)
          acc = fmaf(P.bi[h] + pe_val(t, h), P.Wqkv[h * 192 + tid], acc);
        P.Bt[t * 192 + tid] = acc;
      }
      if (tid < 64) P.Xb[t * 64 + tid] = P.bi[tid] + pe_val(t, tid);
    } else if (t == 16) {
      if (tid < 192) {
        float acc = 0.f;
#pragma unroll 8
        for (int h = 0; h < 64; ++h) acc = fmaf(P.Wi[h], P.Wqkv[h * 192 + tid], acc);
        P.A[tid] = acc;
      }
    } else if (t >= 19 && t < 67) {
      int tb2 = t - 19;   // 0..47
      const float* Wq1 = P.Wqkv + 64 * 192;
#pragma unroll
      for (int e = 0; e < 4; ++e) {
        int gi = tb2 * 1024 + e * 256 + tid;
        float v; int hdst, ldst;
        if (gi < 4096) {
          int o = gi >> 6, i = gi & 63; v = P.Wo0[i * 64 + o];
          hdst = gi; ldst = gi + 4096;
        } else if (gi < 20480) {
          int li = gi - 4096; int o = li >> 6, i = li & 63; v = P.W10[i * 256 + o];
          hdst = 8192 + li; ldst = 24576 + li;
        } else if (gi < 36864) {
          int li = gi - 20480; int o = li >> 8, i = li & 255; v = P.W20[i * 64 + o];
          hdst = 40960 + li; ldst = 57344 + li;
        } else {
          int li = gi - 36864; int o = li >> 6, i = li & 63; v = Wq1[i * 192 + o];
          hdst = 73728 + li; ldst = 86016 + li;
        }
        unsigned u = __float_as_uint(v);
        P.WT[hdst] = (short)(u >> 16);
        P.WT[ldst] = (short)bf16_rne(v - __uint_as_float(u & 0xFFFF0000u));
      }
    }
  }

  // ================= phase A0: layer-0 attention partials ==================
  // self-sufficient (round-11 verified): per-unit score scalars in-block.
  {
    float4* xk4 = (float4*)smem;                   // [64]
    float* peq  = (float*)(smem + 1024);           // [64]
    float* pek  = (float*)(smem + 1280);           // [64]
    float* red  = (float*)(smem + 1536);           // [8]
    float* scal = (float*)(smem + 1568);           // [6]
    for (int u = blk; u < 8 * PAIRS; u += NBLK) {
      __syncthreads();
      int bh = u / PAIRS, pair = u % PAIRS;
      int b = bh >> 2, h = bh & 3;
      int tq = 0, p = pair;
      while (p >= tq + 1) { p -= tq + 1; ++tq; }
      int kt = p;

      if (tid < 64)
        xk4[tid] = *(const float4*)(P.x_seq + (size_t)(b * S_ + kt * N_) + 4 * tid);
      else if (tid < 128)
        peq[tid - 64] = P.bi[tid - 64] + pe_val(tq, tid - 64);
      else if (tid < 192)
        pek[tid - 128] = P.bi[tid - 128] + pe_val(kt, tid - 128);
      __syncthreads();

      {
        float xv = ((const float*)xk4)[tid];
        float mn = xv, mx = xv;
#pragma unroll
        for (int off = 32; off > 0; off >>= 1) {
          mn = fminf(mn, __shfl_xor(mn, off, 64));
          mx = fmaxf(mx, __shfl_xor(mx, off, 64));
        }
        if ((tid & 63) == 0) { red[tid >> 6] = mn; red[4 + (tid >> 6)] = mx; }
      }
      {
        float aq = 0.f, ak = 0.f, bq = 0.f, bk = 0.f;
        if (tid < 16) {
          int cq = h * 16 + tid, ck = 64 + h * 16 + tid;
#pragma unroll 8
          for (int hh = 0; hh < 64; ++hh) {
            float wq = P.Wqkv[hh * 192 + cq], wk = P.Wqkv[hh * 192 + ck];
            aq = fmaf(P.Wi[hh], wq, aq);
            ak = fmaf(P.Wi[hh], wk, ak);
            bq = fmaf(peq[hh], wq, bq);
            bk = fmaf(pek[hh], wk, bk);
          }
          bq += P.bqkv[cq]; bk += P.bqkv[ck];
        }
        float pa = aq * ak, pb = aq * bk, pg = ak * bq, pd = bq * bk;
#pragma unroll
        for (int off = 8; off > 0; off >>= 1) {
          pa += __shfl_xor(pa, off, 64);
          pb += __shfl_xor(pb, off, 64);
          pg += __shfl_xor(pg, off, 64);
          pd += __shfl_xor(pd, off, 64);
        }
        __syncthreads();   // red[] ready
        if (tid == 0) {
          const float k2 = 0.36067376022224085f;  // (1/sqrt(16)) * log2(e)
          scal[0] = k2 * pa; scal[1] = k2 * pb;
          scal[2] = k2 * pg; scal[3] = k2 * pd;
          scal[4] = fminf(fminf(red[0], red[1]), fminf(red[2], red[3]));
          scal[5] = fmaxf(fmaxf(red[4], red[5]), fmaxf(red[6], red[7]));
        }
      }
      __syncthreads();

      float x = P.x_seq[b * S_ + tq * N_ + tid];
      float a = fmaf(scal[0], x, scal[2]);
      float xext = (a >= 0.f) ? scal[5] : scal[4];
      float axext = a * xext;
      float Mg = axext + fmaf(scal[1], x, scal[3]);
      float sp0 = 0.f, sp1 = 0.f, sp2 = 0.f, sp3 = 0.f;
      float sx0 = 0.f, sx1 = 0.f, sx2 = 0.f, sx3 = 0.f;
#pragma unroll 8
      for (int j = 0; j < 64; ++j) {
        float4 xv = xk4[j];
        float e0 = __builtin_amdgcn_exp2f(fmaf(a, xv.x, -axext));
        float e1 = __builtin_amdgcn_exp2f(fmaf(a, xv.y, -axext));
        float e2 = __builtin_amdgcn_exp2f(fmaf(a, xv.z, -axext));
        float e3 = __builtin_amdgcn_exp2f(fmaf(a, xv.w, -axext));
        sp0 += e0; sp1 += e1; sp2 += e2; sp3 += e3;
        sx0 = fmaf(xv.x, e0, sx0); sx1 = fmaf(xv.y, e1, sx1);
        sx2 = fmaf(xv.z, e2, sx2); sx3 = fmaf(xv.w, e3, sx3);
      }
      size_t pb2 = ((size_t)(bh * 16 + tq) * 16 + kt) * 768;
      P.P0[pb2 + tid]       = Mg;
      P.P0[pb2 + 256 + tid] = (sp0 + sp1) + (sp2 + sp3);
      P.P0[pb2 + 512 + tid] = (sx0 + sx1) + (sx2 + sx3);
    }
  }
  grid_barrier(P.BAR, 0);

  // ================= phase F0: fused0 (MFMA) =================
  {
    short (*qbh)[72]  = (short(*)[72])(smem + 0);
    short (*qbl)[72]  = (short(*)[72])(smem + 4608);
    short (*xsh)[72]  = (short(*)[72])(smem + 9216);
    short (*xsl)[72]  = (short(*)[72])(smem + 13824);
    short (*hsh)[264] = (short(*)[264])(smem + 18432);
    short (*hsl)[264] = (short(*)[264])(smem + 35328);
    float (*ys)[68]   = (float(*)[68])(smem + 52224);

    const short* WoTh = P.WT;          const short* WoTl = P.WT + 4096;
    const short* W1Th = P.WT + 8192;   const short* W1Tl = P.WT + 24576;
    const short* W2Th = P.WT + 40960;  const short* W2Tl = P.WT + 57344;
    const short* WqTh = P.WT + 73728;  const short* WqTl = P.WT + 86016;

    int b = blk >> 8, t = (blk >> 4) & 15, n0 = (blk & 15) * 16;
    int gbase = b * S_ + t * N_ + n0;
    int w = tid >> 6, lane = tid & 63, l31 = lane & 31, hi = lane >> 5;

    for (int i = tid; i < 16 * 72; i += 256) {
      (&qbh[16][0])[i] = 0; (&qbl[16][0])[i] = 0;
      (&xsh[16][0])[i] = 0; (&xsl[16][0])[i] = 0;
    }
    for (int i = tid; i < 16 * 264; i += 256) {
      (&hsh[16][0])[i] = 0; (&hsl[16][0])[i] = 0;
    }

    // attention combine (two-pass)
    {
      int r = tid & 15, hh = (tid >> 4) & 3, d4 = tid >> 6;
      int n = n0 + r, bh4 = b * 4 + hh;
      size_t pbase = ((size_t)(bh4 * 16 + t) * 16) * 768 + n;
      float M = -INFINITY;
      for (int kt = 0; kt <= t; ++kt)
        M = fmaxf(M, P.P0[pbase + (size_t)kt * 768]);
      float D = 0.f, SX = 0.f, c0 = 0.f, c1 = 0.f, c2 = 0.f, c3 = 0.f;
      for (int kt = 0; kt <= t; ++kt) {
        size_t pb = pbase + (size_t)kt * 768;
        float wgt = __builtin_amdgcn_exp2f(P.P0[pb] - M);
        float wsp = wgt * P.P0[pb + 256];
        D += wsp;
        SX = fmaf(wgt, P.P0[pb + 512], SX);
        float4 bv = *(const float4*)(P.Bt + kt * 192 + 128 + hh * 16 + d4 * 4);
        c0 = fmaf(wsp, bv.x, c0); c1 = fmaf(wsp, bv.y, c1);
        c2 = fmaf(wsp, bv.z, c2); c3 = fmaf(wsp, bv.w, c3);
      }
      float invD = 1.f / D;
      float4 av = *(const float4*)(P.A + 128 + hh * 16 + d4 * 4);
      float o0 = fmaf(SX, av.x, c0) * invD;
      float o1 = fmaf(SX, av.y, c1) * invD;
      float o2 = fmaf(SX, av.z, c2) * invD;
      float o3 = fmaf(SX, av.w, c3) * invD;
      split4_store(&qbh[r][hh * 16 + d4 * 4], &qbl[r][hh * 16 + d4 * 4],
                   o0, o1, o2, o3);
    }
    __syncthreads();

    // proj
    if (w < 2) {
      f32x16 C = gemm_tile(WoTh, WoTl, w * 32 + l31, 64, 4,
                           &qbh[0][0], &qbl[0][0], 72, l31, hi);
      if (l31 < 16) {
#pragma unroll
        for (int g = 0; g < 4; ++g)
          *(float4*)&ys[l31][w * 32 + g * 8 + 4 * hi] =
              make_float4(C[4 * g], C[4 * g + 1], C[4 * g + 2], C[4 * g + 3]);
      }
    }
    __syncthreads();

    // LN1
    {
      int c = tid & 63, grp = tid >> 6;
      float xb_c = P.Xb[t * 64 + c], wi_c = P.Wi[c], bo_c = P.bo0[c];
      float g1c = P.g10[c], be1c = P.be10[c];
#pragma unroll
      for (int rr = 0; rr < 4; ++rr) {
        int row = grp * 4 + rr;
        float xv = P.x_seq[gbase + row];
        float val = ys[row][c] + bo_c + fmaf(xv, wi_c, xb_c);
        float mean = wave_sum(val) * (1.f / 64.f);
        float dv = val - mean;
        float var = wave_sum(dv * dv) * (1.f / 64.f);
        float xn = dv * rsqrtf(var + 1e-5f) * g1c + be1c;
        unsigned u = __float_as_uint(xn);
        xsh[row][c] = (short)(u >> 16);
        xsl[row][c] = (short)bf16_rne(xn - __uint_as_float(u & 0xFFFF0000u));
      }
    }
    __syncthreads();

    // FFN1
#pragma unroll
    for (int ti = 0; ti < 2; ++ti) {
      int tt = w + 4 * ti;
      f32x16 C = gemm_tile(W1Th, W1Tl, tt * 32 + l31, 64, 4,
                           &xsh[0][0], &xsl[0][0], 72, l31, hi);
      if (l31 < 16) {
#pragma unroll
        for (int g = 0; g < 4; ++g) {
          int cb = tt * 32 + g * 8 + 4 * hi;
          float v0 = fmaxf(C[4 * g + 0] + P.b10[cb + 0], 0.f);
          float v1 = fmaxf(C[4 * g + 1] + P.b10[cb + 1], 0.f);
          float v2 = fmaxf(C[4 * g + 2] + P.b10[cb + 2], 0.f);
          float v3 = fmaxf(C[4 * g + 3] + P.b10[cb + 3], 0.f);
          split4_store(&hsh[l31][cb], &hsl[l31][cb], v0, v1, v2, v3);
        }
      }
    }
    __syncthreads();

    // FFN2
    if (w < 2) {
      f32x16 C = gemm_tile(W2Th, W2Tl, w * 32 + l31, 256, 16,
                           &hsh[0][0], &hsl[0][0], 264, l31, hi);
      if (l31 < 16) {
#pragma unroll
        for (int g = 0; g < 4; ++g)
          *(float4*)&ys[l31][w * 32 + g * 8 + 4 * hi] =
              make_float4(C[4 * g], C[4 * g + 1], C[4 * g + 2], C[4 * g + 3]);
      }
    }
    __syncthreads();

    // LN2
    {
      int c = tid & 63, grp = tid >> 6;
      float b2c = P.b20[c], g2c = P.g20[c], be2c = P.be20[c];
#pragma unroll
      for (int rr = 0; rr < 4; ++rr) {
        int row = grp * 4 + rr;
        float val = ys[row][c] + b2c + rebuild(xsh[row][c], xsl[row][c]);
        float mean = wave_sum(val) * (1.f / 64.f);
        float dv = val - mean;
        float var = wave_sum(dv * dv) * (1.f / 64.f);
        float xn = dv * rsqrtf(var + 1e-5f) * g2c + be2c;
        unsigned u = __float_as_uint(xn);
        qbh[row][c] = (short)(u >> 16);
        qbl[row][c] = (short)bf16_rne(xn - __uint_as_float(u & 0xFFFF0000u));
        if (t == 15) P.X[(size_t)(gbase + row) * 64 + c] = xn;
      }
    }
    __syncthreads();

    // qkv for layer 1
    {
      int tlA = (t == 15) ? w : (2 + w);
      int ntl = (t == 15 && w < 2) ? 2 : 1;
      for (int ti = 0; ti < ntl; ++ti) {
        int tt = ti ? (w + 4) : tlA;
        f32x16 C = gemm_tile(WqTh, WqTl, tt * 32 + l31, 64, 4,
                             &qbh[0][0], &qbl[0][0], 72, l31, hi);
        if (l31 < 16) {
          size_t rb = (size_t)(gbase + l31) * 192;
#pragma unroll
          for (int g = 0; g < 4; ++g) {
            int cb = tt * 32 + g * 8 + 4 * hi;
            float4 o = make_float4(C[4 * g + 0] + P.bq1[cb + 0],
                                   C[4 * g + 1] + P.bq1[cb + 1],
                                   C[4 * g + 2] + P.bq1[cb + 2],
                                   C[4 * g + 3] + P.bq1[cb + 3]);
            *(float4*)&P.QKV[rb + cb] = o;
          }
        }
      }
    }
  }
  grid_barrier(P.BAR, 1);

  // ================= phase A1: layer-1 MFMA attention =================
  if ((blk & 3) == 0) {
    short (*KH)[256][8] = (short(*)[256][8])(smem);
    short (*KL)[256][8] = (short(*)[256][8])(smem + 8192);
    short (*VT)[264]    = (short(*)[264])(smem + 16384);
    int blk1 = blk >> 2;
    int bh = blk1 >> 4, kt = blk1 & 15;
    const int tq = 15;
    int b = bh >> 2, h = bh & 3;
    int w = tid >> 6, lane = tid & 63, l31 = lane & 31, hi = lane >> 5;
    const size_t qkvbase = (size_t)b * S_ * 192;

    for (int i = tid; i < 16 * 264; i += 256) (&VT[16][0])[i] = 0;
    {
      const float* kp = P.QKV + qkvbase + (size_t)(kt * N_ + tid) * 192 + 64 + h * 16;
      float kf[16], vf[16];
#pragma unroll
      for (int i = 0; i < 4; ++i) {
        float4 k4 = *(const float4*)(kp + 4 * i);
        kf[4 * i] = k4.x; kf[4 * i + 1] = k4.y; kf[4 * i + 2] = k4.z; kf[4 * i + 3] = k4.w;
        float4 v4 = *(const float4*)(kp + 64 + 4 * i);
        vf[4 * i] = v4.x; vf[4 * i + 1] = v4.y; vf[4 * i + 2] = v4.z; vf[4 * i + 3] = v4.w;
      }
      short8 kh0, kh1, kl0, kl1;
#pragma unroll
      for (int i = 0; i < 8; ++i) {
        unsigned ht0 = __float_as_uint(kf[i]) & 0xFFFF0000u;
        kh0[i] = (short)(ht0 >> 16);
        kl0[i] = (short)bf16_rne(kf[i] - __uint_as_float(ht0));
        unsigned ht1 = __float_as_uint(kf[i + 8]) & 0xFFFF0000u;
        kh1[i] = (short)(ht1 >> 16);
        kl1[i] = (short)bf16_rne(kf[i + 8] - __uint_as_float(ht1));
      }
      *(short8*)&KH[0][tid][0] = kh0;
      *(short8*)&KH[1][tid][0] = kh1;
      *(short8*)&KL[0][tid][0] = kl0;
      *(short8*)&KL[1][tid][0] = kl1;
#pragma unroll
      for (int i = 0; i < 16; ++i) VT[i][tid] = (short)bf16_rne(vf[i]);
    }
    __syncthreads();

    const float cscale = 0.36067376022224085f;
    short8 Qh[2], Ql[2];
#pragma unroll
    for (int qs = 0; qs < 2; ++qs) {
      int qloc = w * 64 + qs * 32 + l31;
      const float* qp = P.QKV + qkvbase + (size_t)(tq * N_ + qloc) * 192 + h * 16 + 8 * hi;
      float4 a4 = *(const float4*)(qp), b4 = *(const float4*)(qp + 4);
      float qf[8] = {a4.x, a4.y, a4.z, a4.w, b4.x, b4.y, b4.z, b4.w};
#pragma unroll
      for (int i = 0; i < 8; ++i) {
        float q = qf[i] * cscale;
        unsigned ht = __float_as_uint(q) & 0xFFFF0000u;
        Qh[qs][i] = (short)(ht >> 16);
        Ql[qs][i] = (short)bf16_rne(q - __uint_as_float(ht));
      }
    }

    f32x16 O0 = zero16(), O1 = zero16();
    float m[2] = {-INFINITY, -INFINITY}, lsum[2] = {0.f, 0.f};

    for (int ks = 0; ks < 8; ++ks) {
      const short8 Kh = *(const short8*)&KH[hi][ks * 32 + l31][0];
      const short8 Kl = *(const short8*)&KL[hi][ks * 32 + l31][0];
      const short8 Va = *(const short8*)&VT[l31][ks * 32 + 8 * hi];
      const short8 Vb = *(const short8*)&VT[l31][ks * 32 + 8 * hi + 16];

#pragma unroll
      for (int qs = 0; qs < 2; ++qs) {
        f32x16 S = zero16();
        S = __builtin_amdgcn_mfma_f32_32x32x16_bf16(Kh, Qh[qs], S, 0, 0, 0);
        S = __builtin_amdgcn_mfma_f32_32x32x16_bf16(Kl, Qh[qs], S, 0, 0, 0);
        S = __builtin_amdgcn_mfma_f32_32x32x16_bf16(Kh, Ql[qs], S, 0, 0, 0);

        float pm = S[0];
#pragma unroll
        for (int r = 1; r < 16; ++r) pm = fmaxf(pm, S[r]);
        pm = fmaxf(pm, __shfl_xor(pm, 32, 64));
        float mq = m[qs];
        if (__any(pm > mq)) {
          float mn = fmaxf(mq, pm);
          float al = __builtin_amdgcn_exp2f(mq - mn);
          m[qs] = mn; mq = mn;
          lsum[qs] *= al;
          if (qs == 0) {
#pragma unroll
            for (int r = 0; r < 16; ++r) O0[r] *= al;
          } else {
#pragma unroll
            for (int r = 0; r < 16; ++r) O1[r] *= al;
          }
        }
        float pr[16], ps = 0.f;
#pragma unroll
        for (int r = 0; r < 16; ++r) {
          pr[r] = __builtin_amdgcn_exp2f(S[r] - mq);
          ps += pr[r];
        }
        lsum[qs] += ps + __shfl_xor(ps, 32, 64);

        unsigned w01 = pack2(pr[0],  pr[1]);
        unsigned w23 = pack2(pr[2],  pr[3]);
        unsigned w45 = pack2(pr[4],  pr[5]);
        unsigned w67 = pack2(pr[6],  pr[7]);
        unsigned w89 = pack2(pr[8],  pr[9]);
        unsigned wab = pack2(pr[10], pr[11]);
        unsigned wcd = pack2(pr[12], pr[13]);
        unsigned wef = pack2(pr[14], pr[15]);
        unsigned e01 = __shfl_xor(w01, 32, 64), e23 = __shfl_xor(w23, 32, 64);
        unsigned e45 = __shfl_xor(w45, 32, 64), e67 = __shfl_xor(w67, 32, 64);
        unsigned e89 = __shfl_xor(w89, 32, 64), eab = __shfl_xor(wab, 32, 64);
        unsigned ecd = __shfl_xor(wcd, 32, 64), eef = __shfl_xor(wef, 32, 64);
        union { short8 s; unsigned u[4]; } P0u, P1u;
        P0u.u[0] = hi ? e45 : w01;
        P0u.u[1] = hi ? e67 : w23;
        P0u.u[2] = hi ? w45 : e01;
        P0u.u[3] = hi ? w67 : e23;
        P1u.u[0] = hi ? ecd : w89;
        P1u.u[1] = hi ? eef : wab;
        P1u.u[2] = hi ? wcd : e89;
        P1u.u[3] = hi ? wef : eab;

        if (qs == 0) {
          O0 = __builtin_amdgcn_mfma_f32_32x32x16_bf16(Va, P0u.s, O0, 0, 0, 0);
          O0 = __builtin_amdgcn_mfma_f32_32x32x16_bf16(Vb, P1u.s, O0, 0, 0, 0);
        } else {
          O1 = __builtin_amdgcn_mfma_f32_32x32x16_bf16(Va, P0u.s, O1, 0, 0, 0);
          O1 = __builtin_amdgcn_mfma_f32_32x32x16_bf16(Vb, P1u.s, O1, 0, 0, 0);
        }
      }
    }

    int slot = blk1;
#pragma unroll
    for (int qs = 0; qs < 2; ++qs) {
      int qloc = w * 64 + qs * 32 + l31;
      if (lane < 32) {
        P.PM1[(size_t)slot * 256 + qloc] = m[qs];
        P.PL1[(size_t)slot * 256 + qloc] = lsum[qs];
      }
      float* pa = P.PA1 + (size_t)slot * 4096 + (size_t)qloc * 16;
      float4 lo4, hi4;
      if (qs == 0) {
        lo4 = make_float4(O0[0], O0[1], O0[2], O0[3]);
        hi4 = make_float4(O0[4], O0[5], O0[6], O0[7]);
      } else {
        lo4 = make_float4(O1[0], O1[1], O1[2], O1[3]);
        hi4 = make_float4(O1[4], O1[5], O1[6], O1[7]);
      }
      *(float4*)(pa + 4 * hi)     = lo4;
      *(float4*)(pa + 8 + 4 * hi) = hi4;
    }
  }
  grid_barrier(P.BAR, 2);

  // ================= phase F1: fused1 + head =================
  if ((blk & 3) == 0) {
    float (*os)[64]  = (float(*)[64])(smem);
    float (*rs)[64]  = (float(*)[64])(smem + 1024);
    float (*xs)[64]  = (float(*)[64])(smem + 2048);
    float (*x2)[64]  = (float(*)[64])(smem + 3072);
    float (*hs)[256] = (float(*)[256])(smem + 4096);
    float (*h1s)[32] = (float(*)[32])(smem + 8192);
    float (*h2s)[16] = (float(*)[16])(smem + 8704);
    int blk1 = blk >> 2;
    int bb = blk1 >> 6;
    int nbase = (blk1 & 63) * 4;
    int row0 = bb * S_ + 15 * N_ + nbase;
    size_t base = (size_t)row0 * 64;

    {
      int d = tid & 15, r = (tid >> 4) & 3, h = tid >> 6;
      int n = nbase + r;
      int sb = (bb * 4 + h) * 16;
      float M = -INFINITY;
#pragma unroll
      for (int s = 0; s < 16; ++s) M = fmaxf(M, P.PM1[(size_t)(sb + s) * 256 + n]);
      float D = 0.f, od = 0.f;
#pragma unroll
      for (int s = 0; s < 16; ++s) {
        float wgt = __builtin_amdgcn_exp2f(P.PM1[(size_t)(sb + s) * 256 + n] - M);
        D = fmaf(P.PL1[(size_t)(sb + s) * 256 + n], wgt, D);
        od = fmaf(P.PA1[(size_t)(sb + s) * 4096 + (size_t)n * 16 + d], wgt, od);
      }
      os[r][h * 16 + d] = od / D;
      rs[tid >> 6][tid & 63] = P.X[base + tid];
    }
    __syncthreads();

    int c = tid & 63, grp = tid >> 6;
    {
      float a = P.bo1[c];
#pragma unroll 8
      for (int k = 0; k < 64; ++k) a = fmaf(os[grp][k], P.Wo1[k * 64 + c], a);
      float val = a + rs[grp][c];
      float mean = wave_sum(val) * (1.f / 64.f);
      float dv = val - mean;
      float var = wave_sum(dv * dv) * (1.f / 64.f);
      xs[grp][c] = dv * rsqrtf(var + 1e-5f) * P.g11[c] + P.be11[c];
    }
    __syncthreads();

    {
      float am0 = P.b11[tid], am1 = am0, am2 = am0, am3 = am0;
      for (int k4 = 0; k4 < 16; ++k4) {
        float w0 = P.W11[(4 * k4 + 0) * 256 + tid];
        float w1v = P.W11[(4 * k4 + 1) * 256 + tid];
        float w2v = P.W11[(4 * k4 + 2) * 256 + tid];
        float w3v = P.W11[(4 * k4 + 3) * 256 + tid];
        float4 x0 = *(const float4*)&xs[0][4 * k4];
        float4 x1 = *(const float4*)&xs[1][4 * k4];
        float4 x2v = *(const float4*)&xs[2][4 * k4];
        float4 x3 = *(const float4*)&xs[3][4 * k4];
        am0 = fmaf(x0.x, w0, am0); am0 = fmaf(x0.y, w1v, am0);
        am0 = fmaf(x0.z, w2v, am0); am0 = fmaf(x0.w, w3v, am0);
        am1 = fmaf(x1.x, w0, am1); am1 = fmaf(x1.y, w1v, am1);
        am1 = fmaf(x1.z, w2v, am1); am1 = fmaf(x1.w, w3v, am1);
        am2 = fmaf(x2v.x, w0, am2); am2 = fmaf(x2v.y, w1v, am2);
        am2 = fmaf(x2v.z, w2v, am2); am2 = fmaf(x2v.w, w3v, am2);
        am3 = fmaf(x3.x, w0, am3); am3 = fmaf(x3.y, w1v, am3);
        am3 = fmaf(x3.z, w2v, am3); am3 = fmaf(x3.w, w3v, am3);
      }
      hs[0][tid] = fmaxf(am0, 0.f);
      hs[1][tid] = fmaxf(am1, 0.f);
      hs[2][tid] = fmaxf(am2, 0.f);
      hs[3][tid] = fmaxf(am3, 0.f);
    }
    __syncthreads();

    {
      float a = P.b21[c];
      for (int k4 = 0; k4 < 64; ++k4) {
        float w0 = P.W21[(4 * k4 + 0) * 64 + c];
        float w1v = P.W21[(4 * k4 + 1) * 64 + c];
        float w2v = P.W21[(4 * k4 + 2) * 64 + c];
        float w3v = P.W21[(4 * k4 + 3) * 64 + c];
        float4 hv = *(const float4*)&hs[grp][4 * k4];
        a = fmaf(hv.x, w0, a); a = fmaf(hv.y, w1v, a);
        a = fmaf(hv.z, w2v, a); a = fmaf(hv.w, w3v, a);
      }
      float val = a + xs[grp][c];
      float mean = wave_sum(val) * (1.f / 64.f);
      float dv = val - mean;
      float var = wave_sum(dv * dv) * (1.f / 64.f);
      x2[grp][c] = dv * rsqrtf(var + 1e-5f) * P.g21[c] + P.be21[c];
    }
    __syncthreads();

    if (tid < 128) {
      int r = tid >> 5, mid = tid & 31;
      float a = P.db1[mid];
#pragma unroll 8
      for (int k = 0; k < 64; ++k) a = fmaf(x2[r][k], P.dW1[k * 32 + mid], a);
      h1s[r][mid] = fmaxf(a, 0.f);
    }
    __syncthreads();
    if (tid < 64) {
      int r = tid >> 4, low = tid & 15;
      float a = P.db2[low];
#pragma unroll
      for (int k = 0; k < 32; ++k) a = fmaf(h1s[r][k], P.dW2[k * 16 + low], a);
      h2s[r][low] = fmaxf(a, 0.f);
    }
    __syncthreads();
    if (tid < 4) {
      float a = P.db3[0];
#pragma unroll
      for (int k = 0; k < 16; ++k) a = fmaf(h2s[tid][k], P.dW3[k], a);
      P.out[bb * 256 + nbase + tid] = a;
    }
  }
}

}  // namespace

extern "C" void kernel_launch(void* const* d_in, const int* in_sizes, int n_in,
                              void* d_out, int out_size, void* d_ws, size_t ws_size,
                              hipStream_t stream) {
  const float* x_seq = (const float*)d_in[0];
  // d_in[1] = edge_index (unused by reference)
  const float* Wi   = (const float*)d_in[2];
  const float* bi   = (const float*)d_in[3];
  const float* Wqkv = (const float*)d_in[4];
  const float* bqkv = (const float*)d_in[5];
  const float* Wo   = (const float*)d_in[6];
  const float* bo   = (const float*)d_in[7];
  const float* ln1g = (const float*)d_in[8];
  const float* ln1b = (const float*)d_in[9];
  const float* W1   = (const float*)d_in[10];
  const float* b1   = (const float*)d_in[11];
  const float* W2   = (const float*)d_in[12];
  const float* b2   = (const float*)d_in[13];
  const float* ln2g = (const float*)d_in[14];
  const float* ln2b = (const float*)d_in[15];
  const float* dW1  = (const float*)d_in[16];
  const float* db1  = (const float*)d_in[17];
  const float* dW2  = (const float*)d_in[18];
  const float* db2  = (const float*)d_in[19];
  const float* dW3  = (const float*)d_in[20];
  const float* db3  = (const float*)d_in[21];

  float* ws = (float*)d_ws;  // needs >= 17.3 MB

  Args a;
  a.x_seq = x_seq; a.Wi = Wi; a.bi = bi; a.Wqkv = Wqkv; a.bqkv = bqkv;
  a.Wo0 = Wo;          a.bo0 = bo;        a.g10 = ln1g;      a.be10 = ln1b;
  a.W10 = W1;          a.b10 = b1;        a.W20 = W2;        a.b20 = b2;
  a.g20 = ln2g;        a.be20 = ln2b;
  a.Wo1 = Wo + 4096;   a.bo1 = bo + 64;   a.g11 = ln1g + 64; a.be11 = ln1b + 64;
  a.W11 = W1 + 64*256; a.b11 = b1 + 256;  a.W21 = W2 + 256*64; a.b21 = b2 + 64;
  a.g21 = ln2g + 64;   a.be21 = ln2b + 64;
  a.bq1 = bqkv + 192;
  a.dW1 = dW1; a.db1 = db1; a.dW2 = dW2; a.db2 = db2; a.dW3 = dW3; a.db3 = db3;
  a.A = ws + OFF_A;   a.Bt = ws + OFF_BT;  a.Xb = ws + OFF_XB;
  a.X = ws + OFF_X;   a.QKV = ws + OFF_QKV; a.P0 = ws + OFF_P0;
  a.PM1 = ws + OFF_PM1; a.PL1 = ws + OFF_PL1; a.PA1 = ws + OFF_PA1;
  a.out = (float*)d_out;
  a.WT = (short*)(ws + OFF_WT);
  a.BAR = (unsigned*)(ws + OFF_BAR);

  hipMemsetAsync(a.BAR, 0, 16, stream);   // reset the 3 barrier slots
  hipLaunchKernelGGL(k_mega, dim3(NBLK), dim3(256), 0, stream, a);
}

// Round 15
// 72.166 us; speedup vs baseline: 3.2260x; 3.2260x over previous
//
#include <hip/hip_runtime.h>
#include <math.h>

// GlobalTransformer: B=2, T=16, N=256 (S=4096), H=64, NHEAD=4, dh=16, L=2
// Round 15: round-11 structure (best verified: 72.2 us), with setup blocks
// moved to the FRONT of the attn0s grid so they overlap attention blocks.
// 4 dispatches: attn0s+setup | fused0 (MFMA) | attn1 (MFMA) | fused1.

namespace {
constexpr int T_ = 16, N_ = 256, S_ = 4096;
constexpr int PAIRS = 136;   // valid (tq,kt) pairs per bh (layer 0)
constexpr int NSETUP = 65;   // setup blocks (16 Bt/Xb + 1 A + 48 WT)

// ws float offsets (total 4,314,628 floats = 17.3 MB)
constexpr size_t OFF_A    = 0;        // [192]
constexpr size_t OFF_BT   = 192;      // [16][192]
constexpr size_t OFF_XB   = 3264;     // [16][64]
constexpr size_t OFF_X    = 5632;     // [B*S][64] (t=15 rows only)
constexpr size_t OFF_QKV  = 529920;   // [B*S][192]
constexpr size_t OFF_P0   = 2102784;  // [8][16][16][3][256]
constexpr size_t OFF_PM1  = 3675648;  // [128][256]
constexpr size_t OFF_PL1  = 3708416;  // [128][256]
constexpr size_t OFF_PA1  = 3741184;  // [128][256][16]
constexpr size_t OFF_WT   = 4265472;  // 98304 shorts

typedef float  f32x16 __attribute__((ext_vector_type(16)));
typedef short  short8 __attribute__((ext_vector_type(8)));

__device__ inline float wave_sum(float v) {
#pragma unroll
  for (int off = 32; off > 0; off >>= 1) v += __shfl_xor(v, off, 64);
  return v;
}
__device__ inline unsigned bf16_rne(float f) {
  unsigned u = __float_as_uint(f);
  return (u + 0x7FFFu + ((u >> 16) & 1u)) >> 16;
}
__device__ inline unsigned pack2(float a, float b) {   // low<-a, high<-b
  return bf16_rne(a) | (bf16_rne(b) << 16);
}
__device__ inline f32x16 zero16() {
  f32x16 z;
#pragma unroll
  for (int i = 0; i < 16; ++i) z[i] = 0.f;
  return z;
}
__device__ inline float pe_val(int t, int h) {
  float div = __expf((float)(h & ~1) * (-0.14391156831212787f));
  float arg = (float)t * div;
  return (h & 1) ? cosf(arg) : sinf(arg);
}
__device__ inline float rebuild(short h, short l) {
  return __uint_as_float(((unsigned)(unsigned short)h) << 16) +
         __uint_as_float(((unsigned)(unsigned short)l) << 16);
}
__device__ __forceinline__ void split4_store(short* hp, short* lp,
                                             float v0, float v1, float v2, float v3) {
  unsigned u0 = __float_as_uint(v0), u1 = __float_as_uint(v1);
  unsigned u2 = __float_as_uint(v2), u3 = __float_as_uint(v3);
  float r0 = v0 - __uint_as_float(u0 & 0xFFFF0000u);
  float r1 = v1 - __uint_as_float(u1 & 0xFFFF0000u);
  float r2 = v2 - __uint_as_float(u2 & 0xFFFF0000u);
  float r3 = v3 - __uint_as_float(u3 & 0xFFFF0000u);
  *(uint2*)hp = make_uint2((u0 >> 16) | (u1 & 0xFFFF0000u),
                           (u2 >> 16) | (u3 & 0xFFFF0000u));
  *(uint2*)lp = make_uint2(pack2(r0, r1), pack2(r2, r3));
}
__device__ __forceinline__ f32x16 gemm_tile(
    const short* __restrict__ Wh, const short* __restrict__ Wl, int tileRow,
    int inDim, int nkt, const short* Bh, const short* Bl, int bstride,
    int l31, int hi) {
  f32x16 C = zero16();
  for (int kt = 0; kt < nkt; ++kt) {
    int ko = kt * 16 + 8 * hi;
    short8 Ah = *(const short8*)&Wh[tileRow * inDim + ko];
    short8 Al = *(const short8*)&Wl[tileRow * inDim + ko];
    short8 Bh8 = *(const short8*)&Bh[l31 * bstride + ko];
    short8 Bl8 = *(const short8*)&Bl[l31 * bstride + ko];
    C = __builtin_amdgcn_mfma_f32_32x32x16_bf16(Ah, Bh8, C, 0, 0, 0);
    C = __builtin_amdgcn_mfma_f32_32x32x16_bf16(Al, Bh8, C, 0, 0, 0);
    C = __builtin_amdgcn_mfma_f32_32x32x16_bf16(Ah, Bl8, C, 0, 0, 0);
  }
  return C;
}

// -------- dispatch 1: setup blocks FIRST, then self-sufficient attn0 -------
__global__ __launch_bounds__(256, 4) void k_attn0s(
    const float* __restrict__ x_seq, const float* __restrict__ Wi,
    const float* __restrict__ bi, const float* __restrict__ Wqkv,
    const float* __restrict__ bqkv, const float* __restrict__ Wo,
    const float* __restrict__ W1, const float* __restrict__ W2,
    float* __restrict__ A, float* __restrict__ Bt, float* __restrict__ Xb,
    short* __restrict__ WT, float* __restrict__ P0) {
  int blk = blockIdx.x, tid = threadIdx.x;

  if (blk < NSETUP) {               // ---- setup role (scheduled first) ----
    int t = blk;                    // 0..64
    if (t < 16) {
      if (tid < 192) {
        float acc = bqkv[tid];
#pragma unroll 8
        for (int h = 0; h < 64; ++h)
          acc = fmaf(bi[h] + pe_val(t, h), Wqkv[h * 192 + tid], acc);
        Bt[t * 192 + tid] = acc;
      }
      if (tid < 64) Xb[t * 64 + tid] = bi[tid] + pe_val(t, tid);
    } else if (t == 16) {
      if (tid < 192) {
        float acc = 0.f;
#pragma unroll 8
        for (int h = 0; h < 64; ++h) acc = fmaf(Wi[h], Wqkv[h * 192 + tid], acc);
        A[tid] = acc;
      }
    } else {
      int tb2 = t - 17;   // 0..47
      const float* Wq1 = Wqkv + 64 * 192;
#pragma unroll
      for (int e = 0; e < 4; ++e) {
        int gi = tb2 * 1024 + e * 256 + tid;
        float v; int hdst, ldst;
        if (gi < 4096) {
          int o = gi >> 6, i = gi & 63; v = Wo[i * 64 + o];
          hdst = gi; ldst = gi + 4096;
        } else if (gi < 20480) {
          int li = gi - 4096; int o = li >> 6, i = li & 63; v = W1[i * 256 + o];
          hdst = 8192 + li; ldst = 24576 + li;
        } else if (gi < 36864) {
          int li = gi - 20480; int o = li >> 8, i = li & 255; v = W2[i * 64 + o];
          hdst = 40960 + li; ldst = 57344 + li;
        } else {
          int li = gi - 36864; int o = li >> 6, i = li & 63; v = Wq1[i * 192 + o];
          hdst = 73728 + li; ldst = 86016 + li;
        }
        unsigned u = __float_as_uint(v);
        WT[hdst] = (short)(u >> 16);
        WT[ldst] = (short)bf16_rne(v - __uint_as_float(u & 0xFFFF0000u));
      }
    }
    return;
  }

  // ---- attn0 role ----
  __shared__ float4 xk4[64];
  __shared__ float peq[64], pek[64];
  __shared__ float red[8];
  __shared__ float scal[6];   // alpha,beta,gam,delt,mn,mx

  int u0 = blk - NSETUP;
  int bh = u0 / PAIRS, pair = u0 % PAIRS;
  int b = bh >> 2, h = bh & 3;
  int tq = 0, p = pair;
  while (p >= tq + 1) { p -= tq + 1; ++tq; }
  int kt = p;

  if (tid < 64)
    xk4[tid] = *(const float4*)(x_seq + (size_t)(b * S_ + kt * N_) + 4 * tid);
  else if (tid < 128)
    peq[tid - 64] = bi[tid - 64] + pe_val(tq, tid - 64);
  else if (tid < 192)
    pek[tid - 128] = bi[tid - 128] + pe_val(kt, tid - 128);
  __syncthreads();

  // per-(b,kt) min/max of the staged keys
  {
    float xv = ((const float*)xk4)[tid];
    float mn = xv, mx = xv;
#pragma unroll
    for (int off = 32; off > 0; off >>= 1) {
      mn = fminf(mn, __shfl_xor(mn, off, 64));
      mx = fmaxf(mx, __shfl_xor(mx, off, 64));
    }
    if ((tid & 63) == 0) { red[tid >> 6] = mn; red[4 + (tid >> 6)] = mx; }
  }
  // score-table scalars: lanes 0..15 (wave 0)
  {
    float aq = 0.f, ak = 0.f, bq = 0.f, bk = 0.f;
    if (tid < 16) {
      int cq = h * 16 + tid, ck = 64 + h * 16 + tid;
#pragma unroll 8
      for (int hh = 0; hh < 64; ++hh) {
        float wq = Wqkv[hh * 192 + cq], wk = Wqkv[hh * 192 + ck];
        aq = fmaf(Wi[hh], wq, aq);
        ak = fmaf(Wi[hh], wk, ak);
        bq = fmaf(peq[hh], wq, bq);
        bk = fmaf(pek[hh], wk, bk);
      }
      bq += bqkv[cq]; bk += bqkv[ck];
    }
    float pa = aq * ak, pb = aq * bk, pg = ak * bq, pd = bq * bk;
#pragma unroll
    for (int off = 8; off > 0; off >>= 1) {
      pa += __shfl_xor(pa, off, 64);
      pb += __shfl_xor(pb, off, 64);
      pg += __shfl_xor(pg, off, 64);
      pd += __shfl_xor(pd, off, 64);
    }
    __syncthreads();   // red[] ready
    if (tid == 0) {
      const float k2 = 0.36067376022224085f;  // (1/sqrt(16)) * log2(e)
      scal[0] = k2 * pa; scal[1] = k2 * pb;
      scal[2] = k2 * pg; scal[3] = k2 * pd;
      scal[4] = fminf(fminf(red[0], red[1]), fminf(red[2], red[3]));
      scal[5] = fmaxf(fmaxf(red[4], red[5]), fmaxf(red[6], red[7]));
    }
  }
  __syncthreads();

  float x = x_seq[b * S_ + tq * N_ + tid];
  float a = fmaf(scal[0], x, scal[2]);
  float xext = (a >= 0.f) ? scal[5] : scal[4];
  float axext = a * xext;
  float Mg = axext + fmaf(scal[1], x, scal[3]);
  float sp0 = 0.f, sp1 = 0.f, sp2 = 0.f, sp3 = 0.f;
  float sx0 = 0.f, sx1 = 0.f, sx2 = 0.f, sx3 = 0.f;
#pragma unroll 8
  for (int j = 0; j < 64; ++j) {
    float4 xv = xk4[j];
    float e0 = __builtin_amdgcn_exp2f(fmaf(a, xv.x, -axext));
    float e1 = __builtin_amdgcn_exp2f(fmaf(a, xv.y, -axext));
    float e2 = __builtin_amdgcn_exp2f(fmaf(a, xv.z, -axext));
    float e3 = __builtin_amdgcn_exp2f(fmaf(a, xv.w, -axext));
    sp0 += e0; sp1 += e1; sp2 += e2; sp3 += e3;
    sx0 = fmaf(xv.x, e0, sx0); sx1 = fmaf(xv.y, e1, sx1);
    sx2 = fmaf(xv.z, e2, sx2); sx3 = fmaf(xv.w, e3, sx3);
  }
  size_t pb2 = ((size_t)(bh * 16 + tq) * 16 + kt) * 768;
  P0[pb2 + tid]       = Mg;
  P0[pb2 + 256 + tid] = (sp0 + sp1) + (sp2 + sp3);
  P0[pb2 + 512 + tid] = (sx0 + sx1) + (sx2 + sx3);
}

// -------- fused0 (MFMA): combine + proj + LN1 + FFN + LN2 + qkv(layer1) ----
__global__ __launch_bounds__(256, 2) void k_fused0(
    const float* __restrict__ P0, const float* __restrict__ A,
    const float* __restrict__ Bt, const float* __restrict__ Xb,
    const float* __restrict__ x_seq, const float* __restrict__ Wi,
    const float* __restrict__ bo, const float* __restrict__ g1,
    const float* __restrict__ be1, const float* __restrict__ bb1,
    const float* __restrict__ bb2, const float* __restrict__ g2,
    const float* __restrict__ be2, const float* __restrict__ bq1,
    const short* __restrict__ WT,
    float* __restrict__ X, float* __restrict__ QKV) {
  __shared__ short qbh[32][72], qbl[32][72];
  __shared__ short xsh[32][72], xsl[32][72];
  __shared__ short hsh[32][264], hsl[32][264];
  __shared__ float ys[16][68];

  const short* WoTh = WT;          const short* WoTl = WT + 4096;
  const short* W1Th = WT + 8192;   const short* W1Tl = WT + 24576;
  const short* W2Th = WT + 40960;  const short* W2Tl = WT + 57344;
  const short* WqTh = WT + 73728;  const short* WqTl = WT + 86016;

  int blk = blockIdx.x;
  int b = blk >> 8, t = (blk >> 4) & 15, n0 = (blk & 15) * 16;
  int gbase = b * S_ + t * N_ + n0;
  int tid = threadIdx.x;
  int w = tid >> 6, lane = tid & 63, l31 = lane & 31, hi = lane >> 5;

  for (int i = tid; i < 16 * 72; i += 256) {
    (&qbh[16][0])[i] = 0; (&qbl[16][0])[i] = 0;
    (&xsh[16][0])[i] = 0; (&xsl[16][0])[i] = 0;
  }
  for (int i = tid; i < 16 * 264; i += 256) {
    (&hsh[16][0])[i] = 0; (&hsl[16][0])[i] = 0;
  }

  // phase A: attention combine (two-pass)
  {
    int r = tid & 15, hh = (tid >> 4) & 3, d4 = tid >> 6;
    int n = n0 + r, bh4 = b * 4 + hh;
    size_t pbase = ((size_t)(bh4 * 16 + t) * 16) * 768 + n;
    float M = -INFINITY;
    for (int kt = 0; kt <= t; ++kt)
      M = fmaxf(M, P0[pbase + (size_t)kt * 768]);
    float D = 0.f, SX = 0.f, c0 = 0.f, c1 = 0.f, c2 = 0.f, c3 = 0.f;
    for (int kt = 0; kt <= t; ++kt) {
      size_t pb = pbase + (size_t)kt * 768;
      float wgt = __builtin_amdgcn_exp2f(P0[pb] - M);
      float wsp = wgt * P0[pb + 256];
      D += wsp;
      SX = fmaf(wgt, P0[pb + 512], SX);
      float4 bv = *(const float4*)(Bt + kt * 192 + 128 + hh * 16 + d4 * 4);
      c0 = fmaf(wsp, bv.x, c0); c1 = fmaf(wsp, bv.y, c1);
      c2 = fmaf(wsp, bv.z, c2); c3 = fmaf(wsp, bv.w, c3);
    }
    float invD = 1.f / D;
    float4 av = *(const float4*)(A + 128 + hh * 16 + d4 * 4);
    float o0 = fmaf(SX, av.x, c0) * invD;
    float o1 = fmaf(SX, av.y, c1) * invD;
    float o2 = fmaf(SX, av.z, c2) * invD;
    float o3 = fmaf(SX, av.w, c3) * invD;
    split4_store(&qbh[r][hh * 16 + d4 * 4], &qbl[r][hh * 16 + d4 * 4],
                 o0, o1, o2, o3);
  }
  __syncthreads();

  // proj
  if (w < 2) {
    f32x16 C = gemm_tile(WoTh, WoTl, w * 32 + l31, 64, 4,
                         &qbh[0][0], &qbl[0][0], 72, l31, hi);
    if (l31 < 16) {
#pragma unroll
      for (int g = 0; g < 4; ++g)
        *(float4*)&ys[l31][w * 32 + g * 8 + 4 * hi] =
            make_float4(C[4 * g], C[4 * g + 1], C[4 * g + 2], C[4 * g + 3]);
    }
  }
  __syncthreads();

  // LN1
  {
    int c = tid & 63, grp = tid >> 6;
    float xb_c = Xb[t * 64 + c], wi_c = Wi[c], bo_c = bo[c];
    float g1c = g1[c], be1c = be1[c];
#pragma unroll
    for (int rr = 0; rr < 4; ++rr) {
      int row = grp * 4 + rr;
      float xv = x_seq[gbase + row];
      float val = ys[row][c] + bo_c + fmaf(xv, wi_c, xb_c);
      float mean = wave_sum(val) * (1.f / 64.f);
      float dv = val - mean;
      float var = wave_sum(dv * dv) * (1.f / 64.f);
      float xn = dv * rsqrtf(var + 1e-5f) * g1c + be1c;
      unsigned u = __float_as_uint(xn);
      xsh[row][c] = (short)(u >> 16);
      xsl[row][c] = (short)bf16_rne(xn - __uint_as_float(u & 0xFFFF0000u));
    }
  }
  __syncthreads();

  // FFN1
#pragma unroll
  for (int ti = 0; ti < 2; ++ti) {
    int tt = w + 4 * ti;
    f32x16 C = gemm_tile(W1Th, W1Tl, tt * 32 + l31, 64, 4,
                         &xsh[0][0], &xsl[0][0], 72, l31, hi);
    if (l31 < 16) {
#pragma unroll
      for (int g = 0; g < 4; ++g) {
        int cb = tt * 32 + g * 8 + 4 * hi;
        float v0 = fmaxf(C[4 * g + 0] + bb1[cb + 0], 0.f);
        float v1 = fmaxf(C[4 * g + 1] + bb1[cb + 1], 0.f);
        float v2 = fmaxf(C[4 * g + 2] + bb1[cb + 2], 0.f);
        float v3 = fmaxf(C[4 * g + 3] + bb1[cb + 3], 0.f);
        split4_store(&hsh[l31][cb], &hsl[l31][cb], v0, v1, v2, v3);
      }
    }
  }
  __syncthreads();

  // FFN2
  if (w < 2) {
    f32x16 C = gemm_tile(W2Th, W2Tl, w * 32 + l31, 256, 16,
                         &hsh[0][0], &hsl[0][0], 264, l31, hi);
    if (l31 < 16) {
#pragma unroll
      for (int g = 0; g < 4; ++g)
        *(float4*)&ys[l31][w * 32 + g * 8 + 4 * hi] =
            make_float4(C[4 * g], C[4 * g + 1], C[4 * g + 2], C[4 * g + 3]);
    }
  }
  __syncthreads();

  // LN2
  {
    int c = tid & 63, grp = tid >> 6;
    float b2c = bb2[c], g2c = g2[c], be2c = be2[c];
#pragma unroll
    for (int rr = 0; rr < 4; ++rr) {
      int row = grp * 4 + rr;
      float val = ys[row][c] + b2c + rebuild(xsh[row][c], xsl[row][c]);
      float mean = wave_sum(val) * (1.f / 64.f);
      float dv = val - mean;
      float var = wave_sum(dv * dv) * (1.f / 64.f);
      float xn = dv * rsqrtf(var + 1e-5f) * g2c + be2c;
      unsigned u = __float_as_uint(xn);
      qbh[row][c] = (short)(u >> 16);
      qbl[row][c] = (short)bf16_rne(xn - __uint_as_float(u & 0xFFFF0000u));
      if (t == 15) X[(size_t)(gbase + row) * 64 + c] = xn;
    }
  }
  __syncthreads();

  // qkv for layer 1 (K,V always; Q only for t=15 rows)
  {
    int tlA = (t == 15) ? w : (2 + w);
    int ntl = (t == 15 && w < 2) ? 2 : 1;
    for (int ti = 0; ti < ntl; ++ti) {
      int tt = ti ? (w + 4) : tlA;
      f32x16 C = gemm_tile(WqTh, WqTl, tt * 32 + l31, 64, 4,
                           &qbh[0][0], &qbl[0][0], 72, l31, hi);
      if (l31 < 16) {
        size_t rb = (size_t)(gbase + l31) * 192;
#pragma unroll
        for (int g = 0; g < 4; ++g) {
          int cb = tt * 32 + g * 8 + 4 * hi;
          float4 o = make_float4(C[4 * g + 0] + bq1[cb + 0],
                                 C[4 * g + 1] + bq1[cb + 1],
                                 C[4 * g + 2] + bq1[cb + 2],
                                 C[4 * g + 3] + bq1[cb + 3]);
          *(float4*)&QKV[rb + cb] = o;
        }
      }
    }
  }
}

// -------- layer-1 MFMA flash attention (tq=15 only), round-11 verified -----
__global__ __launch_bounds__(256, 4) void k_attn1(const float* __restrict__ QKV,
    float* __restrict__ PM, float* __restrict__ PL, float* __restrict__ PACC) {
  __shared__ short KH[2][256][8];
  __shared__ short KL[2][256][8];
  __shared__ short VT[32][264];
  int blk = blockIdx.x;
  int bh = blk >> 4, kt = blk & 15;
  const int tq = 15;
  int b = bh >> 2, h = bh & 3;
  int tid = threadIdx.x, w = tid >> 6, lane = tid & 63;
  int l31 = lane & 31, hi = lane >> 5;
  const size_t qkvbase = (size_t)b * S_ * 192;

  for (int i = tid; i < 16 * 264; i += 256) (&VT[16][0])[i] = 0;
  {
    const float* kp = QKV + qkvbase + (size_t)(kt * N_ + tid) * 192 + 64 + h * 16;
    float kf[16], vf[16];
#pragma unroll
    for (int i = 0; i < 4; ++i) {
      float4 k4 = *(const float4*)(kp + 4 * i);
      kf[4 * i] = k4.x; kf[4 * i + 1] = k4.y; kf[4 * i + 2] = k4.z; kf[4 * i + 3] = k4.w;
      float4 v4 = *(const float4*)(kp + 64 + 4 * i);
      vf[4 * i] = v4.x; vf[4 * i + 1] = v4.y; vf[4 * i + 2] = v4.z; vf[4 * i + 3] = v4.w;
    }
    short8 kh0, kh1, kl0, kl1;
#pragma unroll
    for (int i = 0; i < 8; ++i) {
      unsigned ht0 = __float_as_uint(kf[i]) & 0xFFFF0000u;
      kh0[i] = (short)(ht0 >> 16);
      kl0[i] = (short)bf16_rne(kf[i] - __uint_as_float(ht0));
      unsigned ht1 = __float_as_uint(kf[i + 8]) & 0xFFFF0000u;
      kh1[i] = (short)(ht1 >> 16);
      kl1[i] = (short)bf16_rne(kf[i + 8] - __uint_as_float(ht1));
    }
    *(short8*)&KH[0][tid][0] = kh0;
    *(short8*)&KH[1][tid][0] = kh1;
    *(short8*)&KL[0][tid][0] = kl0;
    *(short8*)&KL[1][tid][0] = kl1;
#pragma unroll
    for (int i = 0; i < 16; ++i) VT[i][tid] = (short)bf16_rne(vf[i]);
  }
  __syncthreads();

  const float cscale = 0.36067376022224085f;
  short8 Qh[2], Ql[2];
#pragma unroll
  for (int qs = 0; qs < 2; ++qs) {
    int qloc = w * 64 + qs * 32 + l31;
    const float* qp = QKV + qkvbase + (size_t)(tq * N_ + qloc) * 192 + h * 16 + 8 * hi;
    float4 a4 = *(const float4*)(qp), b4 = *(const float4*)(qp + 4);
    float qf[8] = {a4.x, a4.y, a4.z, a4.w, b4.x, b4.y, b4.z, b4.w};
#pragma unroll
    for (int i = 0; i < 8; ++i) {
      float q = qf[i] * cscale;
      unsigned ht = __float_as_uint(q) & 0xFFFF0000u;
      Qh[qs][i] = (short)(ht >> 16);
      Ql[qs][i] = (short)bf16_rne(q - __uint_as_float(ht));
    }
  }

  f32x16 O0 = zero16(), O1 = zero16();
  float m[2] = {-INFINITY, -INFINITY}, lsum[2] = {0.f, 0.f};

  for (int ks = 0; ks < 8; ++ks) {
    const short8 Kh = *(const short8*)&KH[hi][ks * 32 + l31][0];
    const short8 Kl = *(const short8*)&KL[hi][ks * 32 + l31][0];
    const short8 Va = *(const short8*)&VT[l31][ks * 32 + 8 * hi];
    const short8 Vb = *(const short8*)&VT[l31][ks * 32 + 8 * hi + 16];

#pragma unroll
    for (int qs = 0; qs < 2; ++qs) {
      f32x16 S = zero16();
      S = __builtin_amdgcn_mfma_f32_32x32x16_bf16(Kh, Qh[qs], S, 0, 0, 0);
      S = __builtin_amdgcn_mfma_f32_32x32x16_bf16(Kl, Qh[qs], S, 0, 0, 0);
      S = __builtin_amdgcn_mfma_f32_32x32x16_bf16(Kh, Ql[qs], S, 0, 0, 0);

      float pm = S[0];
#pragma unroll
      for (int r = 1; r < 16; ++r) pm = fmaxf(pm, S[r]);
      pm = fmaxf(pm, __shfl_xor(pm, 32, 64));
      float mq = m[qs];
      if (__any(pm > mq)) {
        float mn = fmaxf(mq, pm);
        float al = __builtin_amdgcn_exp2f(mq - mn);
        m[qs] = mn; mq = mn;
        lsum[qs] *= al;
        if (qs == 0) {
#pragma unroll
          for (int r = 0; r < 16; ++r) O0[r] *= al;
        } else {
#pragma unroll
          for (int r = 0; r < 16; ++r) O1[r] *= al;
        }
      }
      float pr[16], ps = 0.f;
#pragma unroll
      for (int r = 0; r < 16; ++r) {
        pr[r] = __builtin_amdgcn_exp2f(S[r] - mq);
        ps += pr[r];
      }
      lsum[qs] += ps + __shfl_xor(ps, 32, 64);

      unsigned w01 = pack2(pr[0],  pr[1]);
      unsigned w23 = pack2(pr[2],  pr[3]);
      unsigned w45 = pack2(pr[4],  pr[5]);
      unsigned w67 = pack2(pr[6],  pr[7]);
      unsigned w89 = pack2(pr[8],  pr[9]);
      unsigned wab = pack2(pr[10], pr[11]);
      unsigned wcd = pack2(pr[12], pr[13]);
      unsigned wef = pack2(pr[14], pr[15]);
      unsigned e01 = __shfl_xor(w01, 32, 64), e23 = __shfl_xor(w23, 32, 64);
      unsigned e45 = __shfl_xor(w45, 32, 64), e67 = __shfl_xor(w67, 32, 64);
      unsigned e89 = __shfl_xor(w89, 32, 64), eab = __shfl_xor(wab, 32, 64);
      unsigned ecd = __shfl_xor(wcd, 32, 64), eef = __shfl_xor(wef, 32, 64);
      union { short8 s; unsigned u[4]; } P0u, P1u;
      P0u.u[0] = hi ? e45 : w01;
      P0u.u[1] = hi ? e67 : w23;
      P0u.u[2] = hi ? w45 : e01;
      P0u.u[3] = hi ? w67 : e23;
      P1u.u[0] = hi ? ecd : w89;
      P1u.u[1] = hi ? eef : wab;
      P1u.u[2] = hi ? wcd : e89;
      P1u.u[3] = hi ? wef : eab;

      if (qs == 0) {
        O0 = __builtin_amdgcn_mfma_f32_32x32x16_bf16(Va, P0u.s, O0, 0, 0, 0);
        O0 = __builtin_amdgcn_mfma_f32_32x32x16_bf16(Vb, P1u.s, O0, 0, 0, 0);
      } else {
        O1 = __builtin_amdgcn_mfma_f32_32x32x16_bf16(Va, P0u.s, O1, 0, 0, 0);
        O1 = __builtin_amdgcn_mfma_f32_32x32x16_bf16(Vb, P1u.s, O1, 0, 0, 0);
      }
    }
  }

  int slot = blk;
#pragma unroll
  for (int qs = 0; qs < 2; ++qs) {
    int qloc = w * 64 + qs * 32 + l31;
    if (lane < 32) {
      PM[(size_t)slot * 256 + qloc] = m[qs];
      PL[(size_t)slot * 256 + qloc] = lsum[qs];
    }
    float* pa = PACC + (size_t)slot * 4096 + (size_t)qloc * 16;
    float4 lo4, hi4;
    if (qs == 0) {
      lo4 = make_float4(O0[0], O0[1], O0[2], O0[3]);
      hi4 = make_float4(O0[4], O0[5], O0[6], O0[7]);
    } else {
      lo4 = make_float4(O1[0], O1[1], O1[2], O1[3]);
      hi4 = make_float4(O1[4], O1[5], O1[6], O1[7]);
    }
    *(float4*)(pa + 4 * hi)     = lo4;
    *(float4*)(pa + 8 + 4 * hi) = hi4;
  }
}

// -------- fused1: combine + proj + LN1 + FFN + LN2 + head (round 11) -------
__global__ __launch_bounds__(256, 2) void k_fused1(
    const float* __restrict__ PM1, const float* __restrict__ PL1,
    const float* __restrict__ PA1,
    const float* __restrict__ Wo, const float* __restrict__ bo,
    const float* __restrict__ g1, const float* __restrict__ be1,
    const float* __restrict__ W1, const float* __restrict__ bb1,
    const float* __restrict__ W2, const float* __restrict__ bb2,
    const float* __restrict__ g2, const float* __restrict__ be2,
    const float* __restrict__ X,
    const float* __restrict__ dW1, const float* __restrict__ db1,
    const float* __restrict__ dW2, const float* __restrict__ db2,
    const float* __restrict__ dW3, const float* __restrict__ db3,
    float* __restrict__ out) {
  __shared__ float os[4][64], rs[4][64], xs[4][64], x2[4][64], hs[4][256];
  __shared__ float h1s[4][32], h2s[4][16];
  int tid = threadIdx.x;
  int bb = blockIdx.x >> 6;
  int nbase = (blockIdx.x & 63) * 4;
  int row0 = bb * S_ + 15 * N_ + nbase;
  size_t base = (size_t)row0 * 64;

  {
    int d = tid & 15, r = (tid >> 4) & 3, h = tid >> 6;
    int n = nbase + r;
    int sb = (bb * 4 + h) * 16;
    float M = -INFINITY;
#pragma unroll
    for (int s = 0; s < 16; ++s) M = fmaxf(M, PM1[(size_t)(sb + s) * 256 + n]);
    float D = 0.f, od = 0.f;
#pragma unroll
    for (int s = 0; s < 16; ++s) {
      float wgt = __builtin_amdgcn_exp2f(PM1[(size_t)(sb + s) * 256 + n] - M);
      D = fmaf(PL1[(size_t)(sb + s) * 256 + n], wgt, D);
      od = fmaf(PA1[(size_t)(sb + s) * 4096 + (size_t)n * 16 + d], wgt, od);
    }
    os[r][h * 16 + d] = od / D;
    rs[tid >> 6][tid & 63] = X[base + tid];
  }
  __syncthreads();

  int c = tid & 63, grp = tid >> 6;
  {
    float a = bo[c];
#pragma unroll 8
    for (int k = 0; k < 64; ++k) a = fmaf(os[grp][k], Wo[k * 64 + c], a);
    float val = a + rs[grp][c];
    float mean = wave_sum(val) * (1.f / 64.f);
    float dv = val - mean;
    float var = wave_sum(dv * dv) * (1.f / 64.f);
    xs[grp][c] = dv * rsqrtf(var + 1e-5f) * g1[c] + be1[c];
  }
  __syncthreads();

  {
    float am0 = bb1[tid], am1 = am0, am2 = am0, am3 = am0;
    for (int k4 = 0; k4 < 16; ++k4) {
      float w0 = W1[(4 * k4 + 0) * 256 + tid];
      float w1v = W1[(4 * k4 + 1) * 256 + tid];
      float w2v = W1[(4 * k4 + 2) * 256 + tid];
      float w3v = W1[(4 * k4 + 3) * 256 + tid];
      float4 x0 = *(const float4*)&xs[0][4 * k4];
      float4 x1 = *(const float4*)&xs[1][4 * k4];
      float4 x2v = *(const float4*)&xs[2][4 * k4];
      float4 x3 = *(const float4*)&xs[3][4 * k4];
      am0 = fmaf(x0.x, w0, am0); am0 = fmaf(x0.y, w1v, am0);
      am0 = fmaf(x0.z, w2v, am0); am0 = fmaf(x0.w, w3v, am0);
      am1 = fmaf(x1.x, w0, am1); am1 = fmaf(x1.y, w1v, am1);
      am1 = fmaf(x1.z, w2v, am1); am1 = fmaf(x1.w, w3v, am1);
      am2 = fmaf(x2v.x, w0, am2); am2 = fmaf(x2v.y, w1v, am2);
      am2 = fmaf(x2v.z, w2v, am2); am2 = fmaf(x2v.w, w3v, am2);
      am3 = fmaf(x3.x, w0, am3); am3 = fmaf(x3.y, w1v, am3);
      am3 = fmaf(x3.z, w2v, am3); am3 = fmaf(x3.w, w3v, am3);
    }
    hs[0][tid] = fmaxf(am0, 0.f);
    hs[1][tid] = fmaxf(am1, 0.f);
    hs[2][tid] = fmaxf(am2, 0.f);
    hs[3][tid] = fmaxf(am3, 0.f);
  }
  __syncthreads();

  {
    float a = bb2[c];
    for (int k4 = 0; k4 < 64; ++k4) {
      float w0 = W2[(4 * k4 + 0) * 64 + c];
      float w1v = W2[(4 * k4 + 1) * 64 + c];
      float w2v = W2[(4 * k4 + 2) * 64 + c];
      float w3v = W2[(4 * k4 + 3) * 64 + c];
      float4 hv = *(const float4*)&hs[grp][4 * k4];
      a = fmaf(hv.x, w0, a); a = fmaf(hv.y, w1v, a);
      a = fmaf(hv.z, w2v, a); a = fmaf(hv.w, w3v, a);
    }
    float val = a + xs[grp][c];
    float mean = wave_sum(val) * (1.f / 64.f);
    float dv = val - mean;
    float var = wave_sum(dv * dv) * (1.f / 64.f);
    x2[grp][c] = dv * rsqrtf(var + 1e-5f) * g2[c] + be2[c];
  }
  __syncthreads();

  if (tid < 128) {
    int r = tid >> 5, mid = tid & 31;
    float a = db1[mid];
#pragma unroll 8
    for (int k = 0; k < 64; ++k) a = fmaf(x2[r][k], dW1[k * 32 + mid], a);
    h1s[r][mid] = fmaxf(a, 0.f);
  }
  __syncthreads();
  if (tid < 64) {
    int r = tid >> 4, low = tid & 15;
    float a = db2[low];
#pragma unroll
    for (int k = 0; k < 32; ++k) a = fmaf(h1s[r][k], dW2[k * 16 + low], a);
    h2s[r][low] = fmaxf(a, 0.f);
  }
  __syncthreads();
  if (tid < 4) {
    float a = db3[0];
#pragma unroll
    for (int k = 0; k < 16; ++k) a = fmaf(h2s[tid][k], dW3[k], a);
    out[bb * 256 + nbase + tid] = a;
  }
}

}  // namespace

extern "C" void kernel_launch(void* const* d_in, const int* in_sizes, int n_in,
                              void* d_out, int out_size, void* d_ws, size_t ws_size,
                              hipStream_t stream) {
  const float* x_seq = (const float*)d_in[0];
  // d_in[1] = edge_index (unused by reference)
  const float* Wi   = (const float*)d_in[2];
  const float* bi   = (const float*)d_in[3];
  const float* Wqkv = (const float*)d_in[4];
  const float* bqkv = (const float*)d_in[5];
  const float* Wo   = (const float*)d_in[6];
  const float* bo   = (const float*)d_in[7];
  const float* ln1g = (const float*)d_in[8];
  const float* ln1b = (const float*)d_in[9];
  const float* W1   = (const float*)d_in[10];
  const float* b1   = (const float*)d_in[11];
  const float* W2   = (const float*)d_in[12];
  const float* b2   = (const float*)d_in[13];
  const float* ln2g = (const float*)d_in[14];
  const float* ln2b = (const float*)d_in[15];
  const float* dW1  = (const float*)d_in[16];
  const float* db1  = (const float*)d_in[17];
  const float* dW2  = (const float*)d_in[18];
  const float* db2  = (const float*)d_in[19];
  const float* dW3  = (const float*)d_in[20];
  const float* db3  = (const float*)d_in[21];

  float* ws   = (float*)d_ws;  // needs >= 17.3 MB
  float* A    = ws + OFF_A;
  float* Bt   = ws + OFF_BT;
  float* Xb   = ws + OFF_XB;
  float* X    = ws + OFF_X;
  float* QKV  = ws + OFF_QKV;
  float* P0   = ws + OFF_P0;
  float* PM1  = ws + OFF_PM1;
  float* PL1  = ws + OFF_PL1;
  float* PA1  = ws + OFF_PA1;
  short* WT   = (short*)(ws + OFF_WT);

  k_attn0s<<<8 * PAIRS + NSETUP, 256, 0, stream>>>(x_seq, Wi, bi, Wqkv, bqkv,
                                                   Wo, W1, W2, A, Bt, Xb, WT, P0);
  k_fused0<<<512, 256, 0, stream>>>(P0, A, Bt, Xb, x_seq, Wi,
                                    bo, ln1g, ln1b, b1, b2, ln2g, ln2b,
                                    bqkv + 192, WT, X, QKV);
  k_attn1<<<128, 256, 0, stream>>>(QKV, PM1, PL1, PA1);
  k_fused1<<<128, 256, 0, stream>>>(PM1, PL1, PA1,
                                    Wo + 4096, bo + 64, ln1g + 64, ln1b + 64,
                                    W1 + 64 * 256, b1 + 256, W2 + 256 * 64, b2 + 64,
                                    ln2g + 64, ln2b + 64, X,
                                    dW1, db1, dW2, db2, dW3, db3, (float*)d_out);
}